// Round 10
// baseline (284.163 us; speedup 1.0000x reference)
//
#include <hip/hip_runtime.h>
#include <math.h>

#define G 24
#define ROWS 577
#define HD 64
#define BH 96
#define EPSF 0.1f
#define COEFF 576.0f
#define BSHIFT 6.3543700408f  // log(575)
#define RPB 8
#define BPI ((ROWS + RPB - 1) / RPB)  // 73
#define NCHUNK 7991196                // 96*577*577/4 (exact)

typedef float f32x4 __attribute__((ext_vector_type(4)));

// ---------------- K1: pure-store ceiling probe (5 full passes) ----------------
__global__ __launch_bounds__(256) void probe_fill(float* __restrict__ out) {
    const size_t stride = (size_t)gridDim.x * 256;
    for (int pass = 0; pass < 5; ++pass) {
        const float val = (float)pass;
        for (size_t i = (size_t)blockIdx.x * 256 + threadIdx.x; i < NCHUNK; i += stride) {
            f32x4 v = { val, val, val, val };
            __builtin_nontemporal_store(v, (f32x4*)out + i);
        }
    }
}

// ---------------- K2: R4-phase4 replica probe (4 passes, dummy tables) ----------------
__global__ __launch_bounds__(256) void probe_tab(float* __restrict__ out) {
    const int bh  = blockIdx.x / BPI;
    const int blk = blockIdx.x - bh * BPI;
    const int r0  = blk * RPB;
    const int Ract = min(RPB, ROWS - r0);
    const int tid = threadIdx.x;

    __shared__ float s_ex0[RPB][28];
    __shared__ float s_ex1[RPB][28];
    for (int e = tid; e < RPB * 28; e += 256) {
        const int rr = e / 28, k = e - 28 * rr;
        s_ex0[rr][k] = 1.0f + 0.001f * (float)e;
        s_ex1[rr][k] = 0.5f + 0.002f * (float)k;
    }
    __syncthreads();

    const size_t base = ((size_t)bh * ROWS + r0) * ROWS;
    const int span  = Ract * ROWS;
    const size_t E  = base + span;
    const size_t S0 = base & ~(size_t)3;
    const int nch   = (int)((E - S0 + 3) >> 2);

    for (int pass = 0; pass < 4; ++pass) {
        for (int idx = tid; idx < nch; idx += 256) {
            const size_t g0 = S0 + (size_t)4 * idx;
            const int e0 = (int)((long long)g0 - (long long)base);
            float v[4];
            #pragma unroll
            for (int t = 0; t < 4; ++t) {
                const int e = e0 + t;
                float val = 0.0f;
                if (e >= 0 && e < span) {
                    const unsigned eu = (unsigned)e;
                    const int rr = (int)(eu / 577u);
                    const int c  = e - rr * 577;
                    if (c > 0) {
                        const unsigned m = (unsigned)(c - 1);
                        const int im = (int)(m / 24u);
                        const int jm = (int)m - im * 24;
                        val = s_ex0[rr][im] * s_ex1[rr][jm];   // R4-style reads
                    }
                }
                v[t] = val + (float)pass;
            }
            if (e0 >= 0 && e0 + 4 <= span) {
                f32x4 pk = { v[0], v[1], v[2], v[3] };
                __builtin_nontemporal_store(pk, (f32x4*)(out + g0));
            } else {
                #pragma unroll
                for (int t = 0; t < 4; ++t) {
                    const int e = e0 + t;
                    if (e >= 0 && e < span) out[g0 + t] = v[t];
                }
            }
        }
    }
}

// ---------------- K3: real kernel — 3 DS-instr per chunk ----------------
__global__ __launch_bounds__(256) void gaussian_augment_kernel(
    const float* __restrict__ q,
    const float* __restrict__ Wv,
    const float* __restrict__ bv,
    const float* __restrict__ Wa,
    const float* __restrict__ ba,
    float* __restrict__ out)
{
    const int bh  = blockIdx.x / BPI;
    const int blk = blockIdx.x - bh * BPI;
    const int r0  = blk * RPB;
    const int Ract = min(RPB, ROWS - r0);
    const int tid = threadIdx.x;

    __shared__ float s_dot[RPB][3];
    __shared__ float s_par[RPB][3];
    __shared__ float s_ex0[RPB][32];   // [0..23] table, [24] = 0 dummy
    __shared__ float s_e1 [RPB][32];   // duplicated: [j] = e1[j mod 24], j=0..27

    // ---- Phase 1: dot products (R4 verbatim) ----
    const int wave = tid >> 6;
    const int lane = tid & 63;
    #pragma unroll
    for (int pass = 0; pass < 2; ++pass) {
        const int rr = wave + 4 * pass;
        if (rr < Ract) {
            const int r = r0 + rr;
            const float* qrow = q + ((size_t)bh * ROWS + r) * HD;
            const float qv = qrow[lane];
            float p0 = qv * Wv[2 * lane + 0];
            float p1 = qv * Wv[2 * lane + 1];
            float p2 = qv * Wa[lane];
            #pragma unroll
            for (int off = 32; off >= 1; off >>= 1) {
                p0 += __shfl_xor(p0, off);
                p1 += __shfl_xor(p1, off);
                p2 += __shfl_xor(p2, off);
            }
            if (lane == 0) {
                s_dot[rr][0] = p0;
                s_dot[rr][1] = p1;
                s_dot[rr][2] = p2;
            }
        }
    }
    __syncthreads();

    // ---- Phase 2: row params (R4 verbatim) ----
    if (tid < Ract) {
        const int r = r0 + tid;
        const float x0 = s_dot[tid][0] + bv[0] - BSHIFT;
        const float x1 = s_dot[tid][1] + bv[1] - BSHIFT;
        const float xa = s_dot[tid][2] + ba[0];
        const float var0 = COEFF / (1.0f + expf(-x0));
        const float var1 = COEFF / (1.0f + expf(-x1));
        s_par[tid][0] = 1.0f / (var0 + EPSF);
        s_par[tid][1] = 1.0f / (var1 + EPSF);
        const float alpha = fmaxf(xa, 0.0f) + log1pf(expf(-fabsf(xa)));
        s_par[tid][2] = (r == 0) ? 0.0f : alpha;
    }
    __syncthreads();

    // ---- Phase 3: tables — ex0[25] (dummy at 24) + e1dup[28] per row ----
    for (int e = tid; e < RPB * 64; e += 256) {
        const int rr = e >> 6;
        const int k  = e & 63;
        if (rr < Ract) {
            const int rg = r0 + rr;
            const int n  = (rg > 0) ? rg - 1 : 0;
            const int in_ = (int)((unsigned)n / 24u);
            const int jn_ = n - in_ * 24;
            if (k < 25) {
                float v = 0.0f;
                if (k < 24) {
                    const float t = (float)(in_ - k);
                    v = s_par[rr][2] * expf(-0.5f * t * t * s_par[rr][0]);
                }
                s_ex0[rr][k] = v;
            } else if (k >= 32 && k < 60) {
                const int j  = k - 32;
                const int jm = (j >= 24) ? j - 24 : j;
                const float t = (float)(jn_ - jm);
                s_e1[rr][j] = expf(-0.5f * t * t * s_par[rr][1]);
            }
        }
    }
    __syncthreads();

    // ---- Phase 4: 3 DS-instr per aligned chunk ----
    const size_t base = ((size_t)bh * ROWS + r0) * ROWS;
    const int span  = Ract * ROWS;
    const size_t E  = base + span;
    const size_t S0 = base & ~(size_t)3;
    const int nch   = (int)((E - S0 + 3) >> 2);

    for (int idx = tid; idx < nch; idx += 256) {
        const size_t g0 = S0 + (size_t)4 * idx;
        const int e0i = 4 * idx - (int)(base - S0);
        const unsigned eu = (unsigned)e0i;
        const int rr = (int)(eu / 577u);
        const int c0 = e0i - rr * 577;
        if (e0i >= 0 && e0i + 4 <= span && c0 >= 1 && c0 <= 573) {
            const int m0  = c0 - 1;
            const int im0 = (int)((unsigned)m0 / 24u);
            const int jm0 = m0 - 24 * im0;
            const float x0 = s_ex0[rr][im0];       // merged read2_b32
            const float x1 = s_ex0[rr][im0 + 1];
            const float* ep = &s_e1[rr][jm0];      // adjacent -> 2x read2_b32
            const float e1a = ep[0], e1b = ep[1], e1c = ep[2], e1d = ep[3];
            f32x4 pk;
            pk[0] = x0 * e1a;
            pk[1] = (jm0 >= 23 ? x1 : x0) * e1b;
            pk[2] = (jm0 >= 22 ? x1 : x0) * e1c;
            pk[3] = (jm0 >= 21 ? x1 : x0) * e1d;
            __builtin_nontemporal_store(pk, (f32x4*)(out + g0));
        } else {
            #pragma unroll
            for (int t = 0; t < 4; ++t) {
                const int e = e0i + t;
                if (e >= 0 && e < span) {
                    const unsigned eu2 = (unsigned)e;
                    const int r2 = (int)(eu2 / 577u);
                    const int c  = e - r2 * 577;
                    float val = 0.0f;
                    if (c > 0) {
                        const unsigned m = (unsigned)(c - 1);
                        const int im = (int)(m / 24u);
                        const int jm = (int)m - im * 24;
                        val = s_ex0[r2][im] * s_e1[r2][jm];
                    }
                    out[g0 + t] = val;
                }
            }
        }
    }
}

extern "C" void kernel_launch(void* const* d_in, const int* in_sizes, int n_in,
                              void* d_out, int out_size, void* d_ws, size_t ws_size,
                              hipStream_t stream) {
    const float* q  = (const float*)d_in[0];
    const float* Wv = (const float*)d_in[1];
    const float* bv = (const float*)d_in[2];
    const float* Wa = (const float*)d_in[3];
    const float* ba = (const float*)d_in[4];
    float* out = (float*)d_out;

    // probes first (their writes are fully overwritten by the real kernel)
    probe_fill<<<2048, 256, 0, stream>>>(out);
    probe_tab<<<BH * BPI, 256, 0, stream>>>(out);
    gaussian_augment_kernel<<<BH * BPI, 256, 0, stream>>>(q, Wv, bv, Wa, ba, out);
}

// Round 11
// 37.740 us; speedup vs baseline: 7.5295x; 7.5295x over previous
//
#include <hip/hip_runtime.h>
#include <math.h>

#define G 24
#define ROWS 577
#define HD 64
#define BH 96
#define EPSF 0.1f
#define COEFF 576.0f
#define BSHIFT 6.3543700408f  // log(575)
#define RPB 8
#define BPI ((ROWS + RPB - 1) / RPB)  // 73

typedef float f32x4 __attribute__((ext_vector_type(4)));

__global__ __launch_bounds__(256) void gaussian_augment_kernel(
    const float* __restrict__ q,
    const float* __restrict__ Wv,
    const float* __restrict__ bv,
    const float* __restrict__ Wa,
    const float* __restrict__ ba,
    float* __restrict__ out)
{
    const int bh  = blockIdx.x / BPI;
    const int blk = blockIdx.x - bh * BPI;
    const int r0  = blk * RPB;
    const int Ract = min(RPB, ROWS - r0);
    const int tid = threadIdx.x;

    __shared__ float s_dot[RPB][3];
    __shared__ float s_par[RPB][3];
    __shared__ float s_ex0[RPB][32];   // [0..23] alpha*exp table, [24] dummy 0
    __shared__ float s_e1 [RPB][32];   // duplicated: [j] = e1[j mod 24], j = 0..27

    // ---- Phase 1: dot products ----
    const int wave = tid >> 6;
    const int lane = tid & 63;
    #pragma unroll
    for (int pass = 0; pass < 2; ++pass) {
        const int rr = wave + 4 * pass;
        if (rr < Ract) {
            const int r = r0 + rr;
            const float* qrow = q + ((size_t)bh * ROWS + r) * HD;
            const float qv = qrow[lane];
            float p0 = qv * Wv[2 * lane + 0];
            float p1 = qv * Wv[2 * lane + 1];
            float p2 = qv * Wa[lane];
            #pragma unroll
            for (int off = 32; off >= 1; off >>= 1) {
                p0 += __shfl_xor(p0, off);
                p1 += __shfl_xor(p1, off);
                p2 += __shfl_xor(p2, off);
            }
            if (lane == 0) {
                s_dot[rr][0] = p0;
                s_dot[rr][1] = p1;
                s_dot[rr][2] = p2;
            }
        }
    }
    __syncthreads();

    // ---- Phase 2: row params, transcendentals once per row ----
    if (tid < Ract) {
        const int r = r0 + tid;
        const float x0 = s_dot[tid][0] + bv[0] - BSHIFT;
        const float x1 = s_dot[tid][1] + bv[1] - BSHIFT;
        const float xa = s_dot[tid][2] + ba[0];
        const float var0 = COEFF / (1.0f + expf(-x0));
        const float var1 = COEFF / (1.0f + expf(-x1));
        s_par[tid][0] = 1.0f / (var0 + EPSF);
        s_par[tid][1] = 1.0f / (var1 + EPSF);
        const float alpha = fmaxf(xa, 0.0f) + log1pf(expf(-fabsf(xa)));
        s_par[tid][2] = (r == 0) ? 0.0f : alpha;   // prefix pad row -> zeros
    }
    __syncthreads();

    // ---- Phase 3: ex0[25] (dummy 0 at 24) + e1dup[28] per row ----
    for (int e = tid; e < RPB * 64; e += 256) {
        const int rr = e >> 6;
        const int k  = e & 63;
        if (rr < Ract) {
            const int rg = r0 + rr;
            const int n  = (rg > 0) ? rg - 1 : 0;
            const int in_ = (int)((unsigned)n / 24u);
            const int jn_ = n - in_ * 24;
            if (k < 25) {
                float v = 0.0f;
                if (k < 24) {
                    const float t = (float)(in_ - k);
                    v = s_par[rr][2] * expf(-0.5f * t * t * s_par[rr][0]);
                }
                s_ex0[rr][k] = v;
            } else if (k >= 32 && k < 60) {
                const int j  = k - 32;
                const int jm = (j >= 24) ? j - 24 : j;
                const float t = (float)(jn_ - jm);
                s_e1[rr][j] = expf(-0.5f * t * t * s_par[rr][1]);
            }
        }
    }
    __syncthreads();

    const size_t base = ((size_t)bh * ROWS + r0) * ROWS;

    // ---- Phase 4a: edges (pad column, head, tail) — 64 threads, <=5 elems/row ----
    if (tid < 8 * RPB) {
        const int rr = tid >> 3;
        const int s  = tid & 7;
        if (rr < Ract) {
            const size_t Sr = base + (size_t)rr * ROWS;
            const int phi = (int)((4 - ((Sr + 1) & 3)) & 3);  // first-aligned-chunk offset
            const int F   = (576 - phi) >> 2;                 // # full aligned chunks
            if (s == 0) {
                out[Sr] = 0.0f;                               // pad column
            } else {
                // s<=phi: head elem m=s-1 ; else tail elem m=4F+s-1
                const int m = (s <= phi) ? (s - 1) : (4 * F + s - 1);
                if (m < 576) {
                    const int im = (int)((unsigned)m / 24u);
                    const int jm = m - 24 * im;
                    out[Sr + 1 + m] = s_ex0[rr][im] * s_e1[rr][jm];
                }
            }
        }
    }

    // ---- Phase 4b: main stream — 32 threads/row, incremental indices ----
    {
        const int rr = tid >> 5;   // 0..7
        const int l  = tid & 31;
        if (rr < Ract) {
            const size_t Sr = base + (size_t)rr * ROWS;
            const int phi = (int)((4 - ((Sr + 1) & 3)) & 3);
            int m  = phi + 4 * l;                   // chunk start (in m-coords)
            int im = (int)((unsigned)m / 24u);      // once per row
            int jm = m - 24 * im;
            float* gp = out + Sr + 1 + m;           // 16B-aligned by construction
            const float* e0p = s_ex0[rr];
            const float* e1p = s_e1[rr];
            #pragma unroll
            for (int it = 0; it < 5; ++it) {
                if (m <= 572) {
                    const float x0  = e0p[im];      // adjacent -> ds_read2_b32
                    const float x1  = e0p[im + 1];
                    const float e1a = e1p[jm];      // adjacent -> 2x ds_read2_b32
                    const float e1b = e1p[jm + 1];
                    const float e1c = e1p[jm + 2];
                    const float e1d = e1p[jm + 3];
                    f32x4 pk;
                    pk[0] = x0 * e1a;
                    pk[1] = (jm >= 23 ? x1 : x0) * e1b;
                    pk[2] = (jm >= 22 ? x1 : x0) * e1c;
                    pk[3] = (jm >= 21 ? x1 : x0) * e1d;
                    __builtin_nontemporal_store(pk, (f32x4*)gp);
                }
                // incremental index update: m += 128 = 5*24 + 8
                m  += 128;
                jm += 8;
                const bool w = (jm >= 24);
                im += w ? 6 : 5;
                jm -= w ? 24 : 0;
                gp += 128;
            }
        }
    }
}

extern "C" void kernel_launch(void* const* d_in, const int* in_sizes, int n_in,
                              void* d_out, int out_size, void* d_ws, size_t ws_size,
                              hipStream_t stream) {
    const float* q  = (const float*)d_in[0];
    const float* Wv = (const float*)d_in[1];
    const float* bv = (const float*)d_in[2];
    const float* Wa = (const float*)d_in[3];
    const float* ba = (const float*)d_in[4];
    float* out = (float*)d_out;

    gaussian_augment_kernel<<<BH * BPI, 256, 0, stream>>>(q, Wv, bv, Wa, ba, out);
}